// Round 1
// baseline (843.670 us; speedup 1.0000x reference)
//
#include <hip/hip_runtime.h>

#define B_SZ 16384
#define NN 7
#define FEAT 512
#define HID 256
#define CTXD 256
#define COMB 2048

typedef __attribute__((ext_vector_type(8))) short short8;
typedef __attribute__((ext_vector_type(4))) float floatx4;
typedef __attribute__((ext_vector_type(4))) unsigned short ushortx4;

__device__ __forceinline__ float bf2f(unsigned short u) {
    union { unsigned int i; float f; } v; v.i = ((unsigned int)u) << 16; return v.f;
}
__device__ __forceinline__ unsigned short f2bf(float f) {
    union { unsigned int i; float f; } v; v.f = f;
    unsigned int i = v.i;
    unsigned int r = (i + 0x7FFFu + ((i >> 16) & 1u)) >> 16;  // RNE
    return (unsigned short)r;
}

// C = A (M x K) * W^T (W: TN x K, fp32 row-major), C (M x TN).
// AT = float (fp32 A) or unsigned short (bf16 A). CT = float or unsigned short.
// Requires M % 64 == 0, K % 32 == 0. TN = NT*16 columns, W has exactly TN rows.
template <typename AT, typename CT, int NT>
__global__ __launch_bounds__(256) void gemm_bt(const AT* __restrict__ A,
                                               const float* __restrict__ W,
                                               CT* __restrict__ C,
                                               int M, int K) {
    constexpr int TN = NT * 16;
    __shared__ __attribute__((aligned(16))) unsigned short As[64][40];
    __shared__ __attribute__((aligned(16))) unsigned short Bs[TN][40];
    const int tid = threadIdx.x;
    const long rowBase = (long)blockIdx.x * 64;
    const int wave = tid >> 6, lane = tid & 63;
    const int quad = lane >> 4, m16 = lane & 15;

    floatx4 acc[NT];
#pragma unroll
    for (int j = 0; j < NT; ++j) acc[j] = (floatx4){0.f, 0.f, 0.f, 0.f};

    for (int k0 = 0; k0 < K; k0 += 32) {
        // stage A tile: 64 rows x 32 k
        for (int idx = tid * 4; idx < 64 * 32; idx += 1024) {
            int r = idx >> 5, c = idx & 31;
            const AT* src = A + (rowBase + r) * (long)K + k0 + c;
            if constexpr (sizeof(AT) == 4) {
                floatx4 v = *(const floatx4*)src;
                As[r][c + 0] = f2bf(v[0]); As[r][c + 1] = f2bf(v[1]);
                As[r][c + 2] = f2bf(v[2]); As[r][c + 3] = f2bf(v[3]);
            } else {
                ushortx4 v = *(const ushortx4*)src;
                As[r][c + 0] = v[0]; As[r][c + 1] = v[1];
                As[r][c + 2] = v[2]; As[r][c + 3] = v[3];
            }
        }
        // stage W tile: TN rows x 32 k (fp32 -> bf16)
        for (int idx = tid * 4; idx < TN * 32; idx += 1024) {
            int r = idx >> 5, c = idx & 31;
            const float* src = W + (long)r * K + k0 + c;
            floatx4 v = *(const floatx4*)src;
            Bs[r][c + 0] = f2bf(v[0]); Bs[r][c + 1] = f2bf(v[1]);
            Bs[r][c + 2] = f2bf(v[2]); Bs[r][c + 3] = f2bf(v[3]);
        }
        __syncthreads();
        // A frag: row = wave*16 + (lane&15), k = quad*8..+8  (measured layout, m89/m92)
        short8 a = *(const short8*)(&As[wave * 16 + m16][quad * 8]);
#pragma unroll
        for (int j = 0; j < NT; ++j) {
            short8 b = *(const short8*)(&Bs[j * 16 + m16][quad * 8]);
            acc[j] = __builtin_amdgcn_mfma_f32_16x16x32_bf16(a, b, acc[j], 0, 0, 0);
        }
        __syncthreads();
    }
    // C/D: row = quad*4 + reg, col = lane&15 (measured, m89/m91)
#pragma unroll
    for (int j = 0; j < NT; ++j) {
#pragma unroll
        for (int i = 0; i < 4; ++i) {
            long m = rowBase + wave * 16 + quad * 4 + i;
            int n = j * 16 + m16;
            float v = acc[j][i];
            if constexpr (sizeof(CT) == 4) C[m * TN + n] = v;
            else                           C[m * TN + n] = f2bf(v);
        }
    }
}

// One block per batch graph. h: (B*7, 256) bf16 pre-activation. Computes GAT
// attention (leaky-relu 0.2, adj mask, softmax w/ nan_to_num) and aggregation,
// writes relu(out) bf16 at out[b*OUTSTRIDE + n*256 + d].
template <int OUTSTRIDE, bool WRITE_ALPHA, bool COPY_CTX>
__global__ __launch_bounds__(256) void attn_kernel(const unsigned short* __restrict__ h,
                                                   const float* __restrict__ adj,
                                                   const float* __restrict__ avec,
                                                   unsigned short* __restrict__ outb,
                                                   float* __restrict__ alpha_out,
                                                   const float* __restrict__ context) {
    __shared__ float hs[NN][HID];
    __shared__ float s_i[NN], s_j[NN];
    __shared__ float alpha_sh[NN][NN];
    const int b = blockIdx.x, tid = threadIdx.x;
    const unsigned short* hb = h + (long)b * (NN * HID);

    for (int idx = tid; idx < NN * HID; idx += 256)
        hs[idx >> 8][idx & 255] = bf2f(hb[idx]);
    if (COPY_CTX)
        outb[(long)b * OUTSTRIDE + NN * HID + tid] = f2bf(context[(long)b * CTXD + tid]);
    __syncthreads();

    const int wave = tid >> 6, lane = tid & 63;
    for (int n = wave; n < NN; n += 4) {
        float pi = 0.f, pj = 0.f;
#pragma unroll
        for (int kk = 0; kk < 4; ++kk) {
            int d = lane + kk * 64;
            float hv = hs[n][d];
            pi += hv * avec[d];
            pj += hv * avec[HID + d];
        }
        for (int off = 32; off; off >>= 1) {
            pi += __shfl_down(pi, off);
            pj += __shfl_down(pj, off);
        }
        if (lane == 0) { s_i[n] = pi; s_j[n] = pj; }
    }
    __syncthreads();

    if (tid < NN) {
        const int i = tid;
        float e[NN];
        float m = -1e30f;
#pragma unroll
        for (int j = 0; j < NN; ++j) {
            float x = s_i[i] + s_j[j];
            x = (x >= 0.f) ? x : 0.2f * x;        // leaky_relu 0.2
            e[j] = (adj[i * NN + j] != 0.f) ? x : -1e30f;
            m = fmaxf(m, e[j]);
        }
        float sum = 0.f;
#pragma unroll
        for (int j = 0; j < NN; ++j) {
            float v = (e[j] <= -1e29f) ? 0.f : __expf(e[j] - m);
            e[j] = v; sum += v;
        }
        float inv = (sum > 0.f) ? 1.f / sum : 0.f;  // nan_to_num path
#pragma unroll
        for (int j = 0; j < NN; ++j) {
            float a = e[j] * inv;
            alpha_sh[i][j] = a;
            if (WRITE_ALPHA) alpha_out[(long)b * (NN * NN) + i * NN + j] = a;
        }
    }
    __syncthreads();

    const int d = tid;
#pragma unroll
    for (int i = 0; i < NN; ++i) {
        float acc = 0.f;
#pragma unroll
        for (int j = 0; j < NN; ++j) acc += alpha_sh[i][j] * hs[j][d];
        outb[(long)b * OUTSTRIDE + i * HID + d] = f2bf(fmaxf(acc, 0.f));  // relu
    }
}

__global__ __launch_bounds__(256) void pack_wh(const float* __restrict__ wh1_w,
                                               const float* __restrict__ rh1_w,
                                               float* __restrict__ Wh) {
    int i = blockIdx.x * 256 + threadIdx.x;
    if (i < 32 * COMB) Wh[i] = wh1_w[i];
    else if (i < 48 * COMB) Wh[i] = rh1_w[i - 32 * COMB];
}

__global__ __launch_bounds__(256) void head_finalize(const float* __restrict__ raw48,
                                                     const float* __restrict__ wh1_b,
                                                     const float* __restrict__ wh2_w,
                                                     const float* __restrict__ wh2_b,
                                                     const float* __restrict__ wh3_w,
                                                     const float* __restrict__ wh3_b,
                                                     const float* __restrict__ rh1_b,
                                                     const float* __restrict__ rh2_w,
                                                     const float* __restrict__ rh2_b,
                                                     const float* __restrict__ base_preds,
                                                     float* __restrict__ out) {
    const int b = blockIdx.x * 256 + threadIdx.x;
    const float* g = raw48 + (long)b * 48;
    float t1[32], r1[16];
#pragma unroll
    for (int k = 0; k < 32; ++k) t1[k] = fmaxf(g[k] + wh1_b[k], 0.f);
#pragma unroll
    for (int k = 0; k < 16; ++k) r1[k] = tanhf(g[32 + k] + rh1_b[k]);
    float t2[16];
#pragma unroll
    for (int j = 0; j < 16; ++j) {
        float s = wh2_b[j];
        for (int k = 0; k < 32; ++k) s += wh2_w[j * 32 + k] * t1[k];
        t2[j] = fmaxf(s, 0.f);
    }
    float rw[5], m = -1e30f;
#pragma unroll
    for (int o = 0; o < 5; ++o) {
        float s = wh3_b[o];
        for (int j = 0; j < 16; ++j) s += wh3_w[o * 16 + j] * t2[j];
        rw[o] = s; m = fmaxf(m, s);
    }
    float se = 0.f;
#pragma unroll
    for (int o = 0; o < 5; ++o) { rw[o] = __expf(rw[o] - m); se += rw[o]; }
    float inv = 1.f / se, wp = 0.f;
#pragma unroll
    for (int o = 0; o < 5; ++o) {
        float w = rw[o] * inv;
        out[B_SZ + (long)b * 5 + o] = w;
        wp += w * base_preds[(long)b * 5 + o];
    }
    float rs = rh2_b[0];
#pragma unroll
    for (int k = 0; k < 16; ++k) rs += rh2_w[k] * r1[k];
    out[b] = fmaxf(wp + rs * 0.05f, 0.05f);
}

extern "C" void kernel_launch(void* const* d_in, const int* in_sizes, int n_in,
                              void* d_out, int out_size, void* d_ws, size_t ws_size,
                              hipStream_t stream) {
    const float* node_feats = (const float*)d_in[0];
    const float* adj        = (const float*)d_in[1];
    const float* context    = (const float*)d_in[2];
    const float* base_preds = (const float*)d_in[3];
    const float* W1         = (const float*)d_in[4];
    const float* a1         = (const float*)d_in[5];
    const float* W2         = (const float*)d_in[6];
    const float* a2         = (const float*)d_in[7];
    const float* wh1_w = (const float*)d_in[8];
    const float* wh1_b = (const float*)d_in[9];
    const float* wh2_w = (const float*)d_in[10];
    const float* wh2_b = (const float*)d_in[11];
    const float* wh3_w = (const float*)d_in[12];
    const float* wh3_b = (const float*)d_in[13];
    const float* rh1_w = (const float*)d_in[14];
    const float* rh1_b = (const float*)d_in[15];
    const float* rh2_w = (const float*)d_in[16];
    const float* rh2_b = (const float*)d_in[17];
    float* out = (float*)d_out;

    // ws layout (bf16 intermediates): ~188 MB total
    char* ws = (char*)d_ws;
    const size_t HB = (size_t)B_SZ * NN * HID * 2;          // 58,720,256 B
    unsigned short* h1       = (unsigned short*)ws;          // [0, HB) : h1, then h2_pre (aliased)
    unsigned short* x2       = (unsigned short*)(ws + HB);   // [HB, 2HB)
    unsigned short* h2pre    = h1;
    unsigned short* combined = (unsigned short*)(ws + 2 * HB);               // B*2048 bf16
    float* raw48 = (float*)(ws + 2 * HB + (size_t)B_SZ * COMB * 2);          // B*48 f32
    float* Wh    = (float*)((char*)raw48 + (size_t)B_SZ * 48 * 4);           // 48*2048 f32

    const int M1 = B_SZ * NN;  // 114688

    pack_wh<<<(48 * COMB) / 256, 256, 0, stream>>>(wh1_w, rh1_w, Wh);

    gemm_bt<float, unsigned short, 16><<<M1 / 64, 256, 0, stream>>>(node_feats, W1, h1, M1, FEAT);

    attn_kernel<NN * HID, false, false><<<B_SZ, 256, 0, stream>>>(h1, adj, a1, x2, nullptr, nullptr);

    gemm_bt<unsigned short, unsigned short, 16><<<M1 / 64, 256, 0, stream>>>(x2, W2, h2pre, M1, HID);

    attn_kernel<COMB, true, true><<<B_SZ, 256, 0, stream>>>(h2pre, adj, a2, combined,
                                                            out + 6 * B_SZ, context);

    gemm_bt<unsigned short, float, 3><<<B_SZ / 64, 256, 0, stream>>>(combined, Wh, raw48, B_SZ, COMB);

    head_finalize<<<B_SZ / 256, 256, 0, stream>>>(raw48, wh1_b, wh2_w, wh2_b, wh3_w, wh3_b,
                                                  rh1_b, rh2_w, rh2_b, base_preds, out);
}

// Round 2
// 572.314 us; speedup vs baseline: 1.4741x; 1.4741x over previous
//
#include <hip/hip_runtime.h>

#define B_SZ 16384
#define NN 7
#define HID 256
#define CTXD 256
#define COMB 2048

typedef __attribute__((ext_vector_type(8))) short short8;
typedef __attribute__((ext_vector_type(4))) float floatx4;
typedef __attribute__((ext_vector_type(4))) unsigned short ushortx4;

__device__ __forceinline__ float bf2f(unsigned short u) {
    union { unsigned int i; float f; } v; v.i = ((unsigned int)u) << 16; return v.f;
}
__device__ __forceinline__ unsigned short f2bf(float f) {  // RNE
    union { unsigned int i; float f; } v; v.f = f;
    return (unsigned short)((v.i + 0x7FFFu + ((v.i >> 16) & 1u)) >> 16);
}
__device__ __forceinline__ unsigned short f2bf_fast(float f) {  // round-half-up (cheap, hot path)
    union { unsigned int i; float f; } v; v.f = f;
    return (unsigned short)((v.i + 0x8000u) >> 16);
}

// async global->LDS, 16B per lane. LDS dst must be wave-uniform base; HW adds lane*16.
__device__ __forceinline__ void gl_lds16(const unsigned short* g, unsigned short* l) {
    __builtin_amdgcn_global_load_lds(
        (const __attribute__((address_space(1))) unsigned int*)g,
        (__attribute__((address_space(3))) unsigned int*)l, 16, 0, 0);
}

// fp32 -> bf16 convert (weights pre-pack)
__global__ __launch_bounds__(256) void cvt_bf16(const float* __restrict__ s,
                                                unsigned short* __restrict__ d, int n) {
    int i = (blockIdx.x * 256 + threadIdx.x) * 4;
    if (i >= n) return;
    floatx4 v = *(const floatx4*)(s + i);
    ushortx4 o = {f2bf(v[0]), f2bf(v[1]), f2bf(v[2]), f2bf(v[3])};
    *(ushortx4*)(d + i) = o;
}

// C (M x N, bf16) = A (M x K) * W^T, W: (N x K) bf16 row-major.
// m97 structure: 128x128 tile, BK=32, 4 waves in 2x2, each wave 64x64 via 4x4 MFMA tiles.
// AFP32: A is fp32, staged manually with convert; else A bf16 via global_load_lds.
template <bool AFP32>
__global__ __launch_bounds__(256) void gemm128(const void* __restrict__ Ap,
                                               const unsigned short* __restrict__ Wb,
                                               unsigned short* __restrict__ C,
                                               int nb, int K) {
    __shared__ __attribute__((aligned(16))) unsigned short As[128 * 32];
    __shared__ __attribute__((aligned(16))) unsigned short Bs[128 * 32];
    const int tid = threadIdx.x;
    const long rowBase = (long)(blockIdx.x / nb) * 128;
    const int colBase = (blockIdx.x % nb) * 128;
    const int N = nb * 128;
    const int wave = tid >> 6, lane = tid & 63;
    const int wm = wave >> 1, wn = wave & 1;
    const int quad = lane >> 4, m16 = lane & 15;
    const int srow = tid >> 2, scol = (tid & 3) * 8;  // lane-order LDS fill: elem = tid*8

    floatx4 acc[4][4];
#pragma unroll
    for (int mt = 0; mt < 4; ++mt)
#pragma unroll
        for (int nt = 0; nt < 4; ++nt) acc[mt][nt] = (floatx4){0.f, 0.f, 0.f, 0.f};

    const unsigned short* Ab = (const unsigned short*)Ap;
    const float* Af = (const float*)Ap;

    for (int k0 = 0; k0 < K; k0 += 32) {
        if constexpr (AFP32) {
            const int r = tid >> 1, c = (tid & 1) * 16;
            const floatx4* src = (const floatx4*)(Af + (rowBase + r) * (long)K + k0 + c);
            floatx4 v0 = src[0], v1 = src[1], v2 = src[2], v3 = src[3];
            short8 s0, s1;
            s0[0] = f2bf_fast(v0[0]); s0[1] = f2bf_fast(v0[1]);
            s0[2] = f2bf_fast(v0[2]); s0[3] = f2bf_fast(v0[3]);
            s0[4] = f2bf_fast(v1[0]); s0[5] = f2bf_fast(v1[1]);
            s0[6] = f2bf_fast(v1[2]); s0[7] = f2bf_fast(v1[3]);
            s1[0] = f2bf_fast(v2[0]); s1[1] = f2bf_fast(v2[1]);
            s1[2] = f2bf_fast(v2[2]); s1[3] = f2bf_fast(v2[3]);
            s1[4] = f2bf_fast(v3[0]); s1[5] = f2bf_fast(v3[1]);
            s1[6] = f2bf_fast(v3[2]); s1[7] = f2bf_fast(v3[3]);
            *(short8*)&As[r * 32 + c] = s0;
            *(short8*)&As[r * 32 + c + 8] = s1;
        } else {
            gl_lds16(Ab + (rowBase + srow) * (long)K + k0 + scol, &As[wave * 512]);
            gl_lds16(Ab + (rowBase + 64 + srow) * (long)K + k0 + scol, &As[2048 + wave * 512]);
        }
        gl_lds16(Wb + (long)(colBase + srow) * K + k0 + scol, &Bs[wave * 512]);
        gl_lds16(Wb + (long)(colBase + 64 + srow) * K + k0 + scol, &Bs[2048 + wave * 512]);
        __syncthreads();
        short8 af[4], bfr[4];
#pragma unroll
        for (int t = 0; t < 4; ++t)
            af[t] = *(const short8*)&As[(wm * 64 + t * 16 + m16) * 32 + quad * 8];
#pragma unroll
        for (int t = 0; t < 4; ++t)
            bfr[t] = *(const short8*)&Bs[(wn * 64 + t * 16 + m16) * 32 + quad * 8];
#pragma unroll
        for (int mt = 0; mt < 4; ++mt)
#pragma unroll
            for (int nt = 0; nt < 4; ++nt)
                acc[mt][nt] = __builtin_amdgcn_mfma_f32_16x16x32_bf16(af[mt], bfr[nt], acc[mt][nt], 0, 0, 0);
        __syncthreads();
    }
#pragma unroll
    for (int mt = 0; mt < 4; ++mt)
#pragma unroll
        for (int nt = 0; nt < 4; ++nt)
#pragma unroll
            for (int i = 0; i < 4; ++i) {
                long m = rowBase + wm * 64 + mt * 16 + quad * 4 + i;
                int n = colBase + wn * 64 + nt * 16 + m16;
                C[m * (long)N + n] = f2bf(acc[mt][nt][i]);
            }
}

// One WAVE per graph. 4 graphs per block. All state in registers + shuffles.
// Column j = lane&7 (j==7 is a masked dummy so 8-lane butterflies work).
template <int OUTSTRIDE, bool WRITE_ALPHA, bool COPY_CTX>
__global__ __launch_bounds__(256) void attn_v2(const unsigned short* __restrict__ h,
                                               const float* __restrict__ adj,
                                               const float* __restrict__ avec,
                                               unsigned short* __restrict__ outb,
                                               float* __restrict__ alpha_out,
                                               const float* __restrict__ context) {
    __shared__ float adjs[NN * NN];
    const int tid = threadIdx.x, wave = tid >> 6, lane = tid & 63;
    if (tid < NN * NN) adjs[tid] = adj[tid];
    __syncthreads();
    const long b = (long)blockIdx.x * 4 + wave;
    const unsigned short* hb = h + b * (NN * HID);

    float hv[NN][4];
#pragma unroll
    for (int n = 0; n < NN; ++n) {
        ushortx4 r = *(const ushortx4*)(hb + n * HID + lane * 4);
        hv[n][0] = bf2f(r[0]); hv[n][1] = bf2f(r[1]);
        hv[n][2] = bf2f(r[2]); hv[n][3] = bf2f(r[3]);
    }
    floatx4 ai = *(const floatx4*)(avec + lane * 4);
    floatx4 aj = *(const floatx4*)(avec + HID + lane * 4);

    float si[NN], sj[NN];
#pragma unroll
    for (int n = 0; n < NN; ++n) {
        float pi = hv[n][0] * ai[0] + hv[n][1] * ai[1] + hv[n][2] * ai[2] + hv[n][3] * ai[3];
        float pj = hv[n][0] * aj[0] + hv[n][1] * aj[1] + hv[n][2] * aj[2] + hv[n][3] * aj[3];
#pragma unroll
        for (int off = 32; off; off >>= 1) {
            pi += __shfl_xor(pi, off);
            pj += __shfl_xor(pj, off);
        }
        si[n] = pi; sj[n] = pj;
    }
    const int j = lane & 7;
    float sjm = sj[0];
    if (j == 1) sjm = sj[1];
    if (j == 2) sjm = sj[2];
    if (j == 3) sjm = sj[3];
    if (j == 4) sjm = sj[4];
    if (j == 5) sjm = sj[5];
    if (j == 6) sjm = sj[6];
    const int jc = (j < 7) ? j : 0;

    float alpha[NN];
#pragma unroll
    for (int i = 0; i < NN; ++i) {
        float x = si[i] + sjm;
        x = (x >= 0.f) ? x : 0.2f * x;                    // leaky_relu 0.2
        bool ok = (j < 7) && (adjs[i * 7 + jc] != 0.f);   // adj mask (+dummy col)
        float e = ok ? x : -1e30f;
        float m = e;
        m = fmaxf(m, __shfl_xor(m, 1, 8));
        m = fmaxf(m, __shfl_xor(m, 2, 8));
        m = fmaxf(m, __shfl_xor(m, 4, 8));
        float ex = ok ? __expf(e - m) : 0.f;
        float s = ex;
        s += __shfl_xor(s, 1, 8);
        s += __shfl_xor(s, 2, 8);
        s += __shfl_xor(s, 4, 8);
        alpha[i] = (s > 0.f) ? ex * __frcp_rn(s) : 0.f;   // nan_to_num path
    }
    if (WRITE_ALPHA && lane < 7) {
#pragma unroll
        for (int i = 0; i < NN; ++i)
            alpha_out[b * (NN * NN) + i * NN + lane] = alpha[i];
    }
    unsigned short* ob = outb + b * OUTSTRIDE;
#pragma unroll
    for (int i = 0; i < NN; ++i) {
        floatx4 o = (floatx4){0.f, 0.f, 0.f, 0.f};
#pragma unroll
        for (int jj = 0; jj < NN; ++jj) {
            float a = __shfl(alpha[i], jj, 8);
            o[0] += a * hv[jj][0]; o[1] += a * hv[jj][1];
            o[2] += a * hv[jj][2]; o[3] += a * hv[jj][3];
        }
        ushortx4 st = {f2bf(fmaxf(o[0], 0.f)), f2bf(fmaxf(o[1], 0.f)),
                       f2bf(fmaxf(o[2], 0.f)), f2bf(fmaxf(o[3], 0.f))};
        *(ushortx4*)(ob + i * HID + lane * 4) = st;       // relu
    }
    if (COPY_CTX) {
        floatx4 c = *(const floatx4*)(context + b * CTXD + lane * 4);
        ushortx4 st = {f2bf(c[0]), f2bf(c[1]), f2bf(c[2]), f2bf(c[3])};
        *(ushortx4*)(ob + NN * HID + lane * 4) = st;
    }
}

// Head GEMM with split-K=4: grid (B/64, 4). 64 rows x 48 cols, K-slice 512.
__global__ __launch_bounds__(256) void head_gemm(const unsigned short* __restrict__ A,
                                                 const unsigned short* __restrict__ Wb,
                                                 float* __restrict__ outp) {
    __shared__ __attribute__((aligned(16))) unsigned short As[64][40];
    __shared__ __attribute__((aligned(16))) unsigned short Bs[48][40];
    const int tid = threadIdx.x;
    const long rowBase = (long)blockIdx.x * 64;
    const int ks = blockIdx.y;
    const int wave = tid >> 6, lane = tid & 63;
    const int quad = lane >> 4, m16 = lane & 15;
    floatx4 acc[3];
#pragma unroll
    for (int t = 0; t < 3; ++t) acc[t] = (floatx4){0.f, 0.f, 0.f, 0.f};
    const int kBeg = ks * 512;
    for (int k0 = kBeg; k0 < kBeg + 512; k0 += 32) {
        {
            int r = tid >> 2, c = (tid & 3) * 8;
            *(short8*)&As[r][c] = *(const short8*)(A + (rowBase + r) * (long)COMB + k0 + c);
        }
        if (tid < 192) {
            int r = tid >> 2, c = (tid & 3) * 8;
            *(short8*)&Bs[r][c] = *(const short8*)(Wb + r * (long)COMB + k0 + c);
        }
        __syncthreads();
        short8 a = *(const short8*)&As[wave * 16 + m16][quad * 8];
#pragma unroll
        for (int t = 0; t < 3; ++t) {
            short8 bfr = *(const short8*)&Bs[t * 16 + m16][quad * 8];
            acc[t] = __builtin_amdgcn_mfma_f32_16x16x32_bf16(a, bfr, acc[t], 0, 0, 0);
        }
        __syncthreads();
    }
    float* op = outp + (long)ks * B_SZ * 48;
#pragma unroll
    for (int t = 0; t < 3; ++t)
#pragma unroll
        for (int i = 0; i < 4; ++i) {
            long m = rowBase + wave * 16 + quad * 4 + i;
            op[m * 48 + t * 16 + m16] = acc[t][i];
        }
}

__global__ __launch_bounds__(256) void head_finalize(const float* __restrict__ rawp,
                                                     const float* __restrict__ wh1_b,
                                                     const float* __restrict__ wh2_w,
                                                     const float* __restrict__ wh2_b,
                                                     const float* __restrict__ wh3_w,
                                                     const float* __restrict__ wh3_b,
                                                     const float* __restrict__ rh1_b,
                                                     const float* __restrict__ rh2_w,
                                                     const float* __restrict__ rh2_b,
                                                     const float* __restrict__ base_preds,
                                                     float* __restrict__ out) {
    const int b = blockIdx.x * 256 + threadIdx.x;
    const size_t P = (size_t)B_SZ * 48;
    const float* g0 = rawp + (long)b * 48;
    float t1[32], r1[16];
#pragma unroll
    for (int k = 0; k < 32; ++k) {
        float g = g0[k] + g0[P + k] + g0[2 * P + k] + g0[3 * P + k];
        t1[k] = fmaxf(g + wh1_b[k], 0.f);
    }
#pragma unroll
    for (int k = 0; k < 16; ++k) {
        float g = g0[32 + k] + g0[P + 32 + k] + g0[2 * P + 32 + k] + g0[3 * P + 32 + k];
        r1[k] = tanhf(g + rh1_b[k]);
    }
    float t2[16];
#pragma unroll
    for (int jj = 0; jj < 16; ++jj) {
        float s = wh2_b[jj];
        for (int k = 0; k < 32; ++k) s += wh2_w[jj * 32 + k] * t1[k];
        t2[jj] = fmaxf(s, 0.f);
    }
    float rw[5], m = -1e30f;
#pragma unroll
    for (int o = 0; o < 5; ++o) {
        float s = wh3_b[o];
        for (int jj = 0; jj < 16; ++jj) s += wh3_w[o * 16 + jj] * t2[jj];
        rw[o] = s; m = fmaxf(m, s);
    }
    float se = 0.f;
#pragma unroll
    for (int o = 0; o < 5; ++o) { rw[o] = __expf(rw[o] - m); se += rw[o]; }
    float inv = 1.f / se, wp = 0.f;
#pragma unroll
    for (int o = 0; o < 5; ++o) {
        float w = rw[o] * inv;
        out[B_SZ + (long)b * 5 + o] = w;
        wp += w * base_preds[(long)b * 5 + o];
    }
    float rs = rh2_b[0];
#pragma unroll
    for (int k = 0; k < 16; ++k) rs += rh2_w[k] * r1[k];
    out[b] = fmaxf(wp + rs * 0.05f, 0.05f);
}

extern "C" void kernel_launch(void* const* d_in, const int* in_sizes, int n_in,
                              void* d_out, int out_size, void* d_ws, size_t ws_size,
                              hipStream_t stream) {
    const float* node_feats = (const float*)d_in[0];
    const float* adj        = (const float*)d_in[1];
    const float* context    = (const float*)d_in[2];
    const float* base_preds = (const float*)d_in[3];
    const float* W1         = (const float*)d_in[4];
    const float* a1         = (const float*)d_in[5];
    const float* W2         = (const float*)d_in[6];
    const float* a2         = (const float*)d_in[7];
    const float* wh1_w = (const float*)d_in[8];
    const float* wh1_b = (const float*)d_in[9];
    const float* wh2_w = (const float*)d_in[10];
    const float* wh2_b = (const float*)d_in[11];
    const float* wh3_w = (const float*)d_in[12];
    const float* wh3_b = (const float*)d_in[13];
    const float* rh1_w = (const float*)d_in[14];
    const float* rh1_b = (const float*)d_in[15];
    const float* rh2_w = (const float*)d_in[16];
    const float* rh2_b = (const float*)d_in[17];
    float* out = (float*)d_out;

    // ws layout (~185 MB)
    char* ws = (char*)d_ws;
    const size_t HB = (size_t)B_SZ * NN * HID * 2;                  // 58,720,256 B
    unsigned short* h1       = (unsigned short*)ws;                  // [0, HB); reused as h2pre
    unsigned short* x2       = (unsigned short*)(ws + HB);           // [HB, 2HB); later aliased by rawp
    unsigned short* h2pre    = h1;
    unsigned short* combined = (unsigned short*)(ws + 2 * HB);       // B*2048 bf16 = 64 MB
    float* rawp = (float*)(ws + HB);                                 // 4*B*48 f32 = 12.6 MB (x2 dead)
    unsigned short* W1b = (unsigned short*)(ws + 2 * HB + (size_t)B_SZ * COMB * 2);
    unsigned short* W2b = W1b + 256 * 512;
    unsigned short* Whb = W2b + 256 * 256;                           // 48 x 2048

    const int M1 = B_SZ * NN;  // 114688

    cvt_bf16<<<128, 256, 0, stream>>>(W1, W1b, 256 * 512);
    cvt_bf16<<<64, 256, 0, stream>>>(W2, W2b, 256 * 256);
    cvt_bf16<<<64, 256, 0, stream>>>(wh1_w, Whb, 32 * 2048);
    cvt_bf16<<<32, 256, 0, stream>>>(rh1_w, Whb + 32 * 2048, 16 * 2048);

    gemm128<true><<<(M1 / 128) * 2, 256, 0, stream>>>(node_feats, W1b, h1, 2, 512);

    attn_v2<NN * HID, false, false><<<B_SZ / 4, 256, 0, stream>>>(h1, adj, a1, x2, nullptr, nullptr);

    gemm128<false><<<(M1 / 128) * 2, 256, 0, stream>>>(x2, W2b, h2pre, 2, 256);

    attn_v2<COMB, true, true><<<B_SZ / 4, 256, 0, stream>>>(h2pre, adj, a2, combined,
                                                            out + 6 * B_SZ, context);

    head_gemm<<<dim3(B_SZ / 64, 4), 256, 0, stream>>>(combined, Whb, rawp);

    head_finalize<<<B_SZ / 256, 256, 0, stream>>>(rawp, wh1_b, wh2_w, wh2_b, wh3_w, wh3_b,
                                                  rh1_b, rh2_w, rh2_b, base_preds, out);
}

// Round 3
// 541.748 us; speedup vs baseline: 1.5573x; 1.0564x over previous
//
#include <hip/hip_runtime.h>

#define B_SZ 16384
#define NN 7
#define HID 256
#define COMB 2048

typedef __attribute__((ext_vector_type(8))) short short8;
typedef __attribute__((ext_vector_type(4))) float floatx4;
typedef __attribute__((ext_vector_type(4))) unsigned short ushortx4;
typedef unsigned short us;

__device__ __forceinline__ float bf2f(us u) {
    union { unsigned int i; float f; } v; v.i = ((unsigned int)u) << 16; return v.f;
}
__device__ __forceinline__ us f2bf(float f) {  // RNE
    union { unsigned int i; float f; } v; v.f = f;
    return (us)((v.i + 0x7FFFu + ((v.i >> 16) & 1u)) >> 16);
}
__device__ __forceinline__ us f2bf_fast(float f) {  // round-half-up (hot path)
    union { unsigned int i; float f; } v; v.f = f;
    return (us)((v.i + 0x8000u) >> 16);
}
__device__ __forceinline__ void gl_lds16(const us* g, us* l) {
    __builtin_amdgcn_global_load_lds(
        (const __attribute__((address_space(1))) unsigned int*)g,
        (__attribute__((address_space(3))) unsigned int*)l, 16, 0, 0);
}

// Pack W1 (131072), W2 (65536), wh1_w (65536), rh1_w (32768) fp32 -> contiguous bf16 dst.
__global__ __launch_bounds__(256) void pack_weights(const float* __restrict__ W1,
                                                    const float* __restrict__ W2,
                                                    const float* __restrict__ wh1,
                                                    const float* __restrict__ rh1,
                                                    us* __restrict__ dst) {
    int i = (blockIdx.x * 256 + threadIdx.x) * 4;
    if (i >= 294912) return;
    const float* src; int off;
    if (i < 131072)      { src = W1;  off = i; }
    else if (i < 196608) { src = W2;  off = i - 131072; }
    else if (i < 262144) { src = wh1; off = i - 196608; }
    else                 { src = rh1; off = i - 262144; }
    floatx4 v = *(const floatx4*)(src + off);
    ushortx4 o = {f2bf(v[0]), f2bf(v[1]), f2bf(v[2]), f2bf(v[3])};
    *(ushortx4*)(dst + i) = o;
}

// GAT attention for ONE graph, executed by one 64-lane wave. hb: 7x256 bf16 (LDS),
// row stride SRC_STRIDE. Writes relu'd aggregate to dst (stride dstStride); optional alpha.
// Verified structure from round 2 (lane&7 = column j, j==7 masked dummy).
template <int SRC_STRIDE, bool WRITE_ALPHA>
__device__ __forceinline__ void attn_graph(const us* hb, const float* adjs, const float* avec,
                                           us* dst, int dstStride, float* alpha_dst, int lane) {
    float hv[NN][4];
#pragma unroll
    for (int n = 0; n < NN; ++n) {
        ushortx4 r = *(const ushortx4*)(hb + n * SRC_STRIDE + lane * 4);
        hv[n][0] = bf2f(r[0]); hv[n][1] = bf2f(r[1]);
        hv[n][2] = bf2f(r[2]); hv[n][3] = bf2f(r[3]);
    }
    floatx4 ai = *(const floatx4*)(avec + lane * 4);
    floatx4 aj = *(const floatx4*)(avec + HID + lane * 4);
    float si[NN], sj[NN];
#pragma unroll
    for (int n = 0; n < NN; ++n) {
        float pi = hv[n][0] * ai[0] + hv[n][1] * ai[1] + hv[n][2] * ai[2] + hv[n][3] * ai[3];
        float pj = hv[n][0] * aj[0] + hv[n][1] * aj[1] + hv[n][2] * aj[2] + hv[n][3] * aj[3];
#pragma unroll
        for (int off = 32; off; off >>= 1) {
            pi += __shfl_xor(pi, off);
            pj += __shfl_xor(pj, off);
        }
        si[n] = pi; sj[n] = pj;
    }
    const int j = lane & 7;
    float sjm = sj[0];
    if (j == 1) sjm = sj[1];
    if (j == 2) sjm = sj[2];
    if (j == 3) sjm = sj[3];
    if (j == 4) sjm = sj[4];
    if (j == 5) sjm = sj[5];
    if (j == 6) sjm = sj[6];
    const int jc = (j < 7) ? j : 0;
    float alpha[NN];
#pragma unroll
    for (int i = 0; i < NN; ++i) {
        float x = si[i] + sjm;
        x = (x >= 0.f) ? x : 0.2f * x;                     // leaky_relu 0.2
        bool ok = (j < 7) && (adjs[i * 7 + jc] != 0.f);    // adj mask + dummy col
        float e = ok ? x : -1e30f;
        float m = e;
        m = fmaxf(m, __shfl_xor(m, 1, 8));
        m = fmaxf(m, __shfl_xor(m, 2, 8));
        m = fmaxf(m, __shfl_xor(m, 4, 8));
        float ex = ok ? __expf(e - m) : 0.f;
        float s = ex;
        s += __shfl_xor(s, 1, 8);
        s += __shfl_xor(s, 2, 8);
        s += __shfl_xor(s, 4, 8);
        alpha[i] = (s > 0.f) ? ex * __frcp_rn(s) : 0.f;    // nan_to_num path
    }
    if (WRITE_ALPHA && lane < 7) {
#pragma unroll
        for (int i = 0; i < NN; ++i) alpha_dst[i * NN + lane] = alpha[i];
    }
#pragma unroll
    for (int i = 0; i < NN; ++i) {
        floatx4 o = (floatx4){0.f, 0.f, 0.f, 0.f};
#pragma unroll
        for (int jj = 0; jj < NN; ++jj) {
            float a = __shfl(alpha[i], jj, 8);
            o[0] += a * hv[jj][0]; o[1] += a * hv[jj][1];
            o[2] += a * hv[jj][2]; o[3] += a * hv[jj][3];
        }
        ushortx4 st = {f2bf(fmaxf(o[0], 0.f)), f2bf(fmaxf(o[1], 0.f)),
                       f2bf(fmaxf(o[2], 0.f)), f2bf(fmaxf(o[3], 0.f))};
        *(ushortx4*)(dst + i * dstStride + lane * 4) = st;   // relu
    }
}

// ---------------- Kernel A: GEMM1 (fp32 A) + attention 1 -> x2 ----------------
// 1024 blocks x 512 threads. Block = 16 graphs = 112 rows; full N=256 in-block.
// LDS tiles use k-major 16B-chunk layout: chunk(row,khalf) at region(row>>4)*512
// + (khalf*16 + (row&15))*8 shorts -> conflict-free ds_read_b128 fragments.
__global__ __launch_bounds__(512) void fused_g1(const float* __restrict__ Af,
                                                const us* __restrict__ W1b,
                                                const float* __restrict__ adj,
                                                const float* __restrict__ avec,
                                                us* __restrict__ x2g) {
    extern __shared__ __attribute__((aligned(16))) char smem[];
    us* As = (us*)smem;                    // 7 regions  (112 rows) : 7168 B
    us* Bs = (us*)(smem + 7168);           // 16 regions (256 rows) : 16384 B
    us* hs = (us*)(smem + 23552);          // 112 x 256 bf16       : 57344 B
    float* adjs = (float*)(smem + 80896);  // 49 f32

    const int tid = threadIdx.x;
    const int wave = tid >> 6, lane = tid & 63;
    const int quad = lane >> 4, m16 = lane & 15;
    const long rowBase = (long)blockIdx.x * 112;
    if (tid < 49) adjs[tid] = adj[tid];

    floatx4 acc[7][2];
#pragma unroll
    for (int rt = 0; rt < 7; ++rt)
#pragma unroll
        for (int ct = 0; ct < 2; ++ct) acc[rt][ct] = (floatx4){0.f, 0.f, 0.f, 0.f};

    for (int k0 = 0; k0 < 512; k0 += 32) {
        if (tid < 448) {  // stage A: 112 rows x 32 k, fp32 -> bf16, one 16B chunk/thread
            int r = tid >> 2, kh = tid & 3;
            const floatx4* src = (const floatx4*)(Af + (rowBase + r) * 512 + k0 + kh * 8);
            floatx4 v0 = src[0], v1 = src[1];
            short8 s;
            s[0] = f2bf_fast(v0[0]); s[1] = f2bf_fast(v0[1]);
            s[2] = f2bf_fast(v0[2]); s[3] = f2bf_fast(v0[3]);
            s[4] = f2bf_fast(v1[0]); s[5] = f2bf_fast(v1[1]);
            s[6] = f2bf_fast(v1[2]); s[7] = f2bf_fast(v1[3]);
            *(short8*)&As[(r >> 4) * 512 + (kh * 16 + (r & 15)) * 8] = s;
        }
        {   // stage B (W1b, 256 rows): 2 DMA calls/wave, 16 rows each
            int b1 = wave * 16, b2 = 128 + wave * 16;
            gl_lds16(W1b + (long)(b1 + (lane & 15)) * 512 + k0 + (lane >> 4) * 8, &Bs[b1 * 32]);
            gl_lds16(W1b + (long)(b2 + (lane & 15)) * 512 + k0 + (lane >> 4) * 8, &Bs[b2 * 32]);
        }
        __syncthreads();
        short8 af[7], bf[2];
#pragma unroll
        for (int rt = 0; rt < 7; ++rt)
            af[rt] = *(const short8*)&As[rt * 512 + (quad * 16 + m16) * 8];
#pragma unroll
        for (int ct = 0; ct < 2; ++ct)
            bf[ct] = *(const short8*)&Bs[(wave * 2 + ct) * 512 + (quad * 16 + m16) * 8];
#pragma unroll
        for (int rt = 0; rt < 7; ++rt)
#pragma unroll
            for (int ct = 0; ct < 2; ++ct)
                acc[rt][ct] = __builtin_amdgcn_mfma_f32_16x16x32_bf16(af[rt], bf[ct], acc[rt][ct], 0, 0, 0);
        __syncthreads();
    }
    // h1 (pre-relu) -> LDS. C-layout: row = quad*4+i, col = lane&15.
#pragma unroll
    for (int rt = 0; rt < 7; ++rt)
#pragma unroll
        for (int ct = 0; ct < 2; ++ct)
#pragma unroll
            for (int i = 0; i < 4; ++i)
                hs[(rt * 16 + quad * 4 + i) * 256 + wave * 32 + ct * 16 + m16] = f2bf(acc[rt][ct][i]);
    __syncthreads();
    // attention 1: 8 waves x 2 graphs
#pragma unroll
    for (int gg = 0; gg < 2; ++gg) {
        int gl = wave * 2 + gg;
        long b = (long)blockIdx.x * 16 + gl;
        attn_graph<256, false>(&hs[gl * 7 * 256], adjs, avec,
                               x2g + b * 7 * 256, 256, nullptr, lane);
    }
}

// ------- Kernel B: GEMM2 + attention 2 + head GEMM + reduce + finalize -------
__global__ __launch_bounds__(512) void fused_rest(const us* __restrict__ x2g,
                                                  const us* __restrict__ W2b,
                                                  const us* __restrict__ Whb,
                                                  const float* __restrict__ adj,
                                                  const float* __restrict__ avec,
                                                  const float* __restrict__ context,
                                                  const float* __restrict__ wh1_b,
                                                  const float* __restrict__ wh2_w,
                                                  const float* __restrict__ wh2_b,
                                                  const float* __restrict__ wh3_w,
                                                  const float* __restrict__ wh3_b,
                                                  const float* __restrict__ rh1_b,
                                                  const float* __restrict__ rh2_w,
                                                  const float* __restrict__ rh2_b,
                                                  const float* __restrict__ base_preds,
                                                  float* __restrict__ out) {
    extern __shared__ __attribute__((aligned(16))) char smem[];
    us* As = (us*)smem;                      // 8 regions (128 rows, 16 over-fetched) : 8192 B
    us* Bs = (us*)(smem + 8192);             // 16 regions (256 rows)                 : 16384 B
    us* hs = (us*)(smem + 24576);            // 112 x 260 bf16 (pad for head frags)   : 58240 B
    us* ctxs = (us*)(smem + 82816);          // 16 x 260 bf16                         : 8320 B
    float* red = (float*)(smem + 91136);     // 8 x 768 f32 partials                  : 24576 B
    float* fin = (float*)(smem + 115712);    // 768 f32 final                         : 3072 B
    float* adjs = (float*)(smem + 118784);   // 49 f32

    const int tid = threadIdx.x;
    const int wave = tid >> 6, lane = tid & 63;
    const int quad = lane >> 4, m16 = lane & 15;
    const long rowBase = (long)blockIdx.x * 112;
    const long gbase = (long)blockIdx.x * 16;
    if (tid < 49) adjs[tid] = adj[tid];
    {   // stage context: 16 x 256 fp32 -> bf16 (row stride 260)
        int r = tid >> 5, c = (tid & 31) * 8;
        const floatx4* src = (const floatx4*)(context + (gbase + r) * 256 + c);
        floatx4 v0 = src[0], v1 = src[1];
        short8 s;
        s[0] = f2bf(v0[0]); s[1] = f2bf(v0[1]); s[2] = f2bf(v0[2]); s[3] = f2bf(v0[3]);
        s[4] = f2bf(v1[0]); s[5] = f2bf(v1[1]); s[6] = f2bf(v1[2]); s[7] = f2bf(v1[3]);
        *(short8*)&ctxs[r * 260 + c] = s;
    }

    floatx4 acc[7][2];
#pragma unroll
    for (int rt = 0; rt < 7; ++rt)
#pragma unroll
        for (int ct = 0; ct < 2; ++ct) acc[rt][ct] = (floatx4){0.f, 0.f, 0.f, 0.f};

    for (int k0 = 0; k0 < 256; k0 += 32) {
        // stage A (x2): 1 DMA call/wave, 16 rows (rows 112..127 over-fetch, unused)
        gl_lds16(x2g + (rowBase + wave * 16 + (lane & 15)) * 256 + k0 + (lane >> 4) * 8,
                 &As[wave * 512]);
        {   // stage B (W2b): 2 calls/wave
            int b1 = wave * 16, b2 = 128 + wave * 16;
            gl_lds16(W2b + (long)(b1 + (lane & 15)) * 256 + k0 + (lane >> 4) * 8, &Bs[b1 * 32]);
            gl_lds16(W2b + (long)(b2 + (lane & 15)) * 256 + k0 + (lane >> 4) * 8, &Bs[b2 * 32]);
        }
        __syncthreads();
        short8 af[7], bf[2];
#pragma unroll
        for (int rt = 0; rt < 7; ++rt)
            af[rt] = *(const short8*)&As[rt * 512 + (quad * 16 + m16) * 8];
#pragma unroll
        for (int ct = 0; ct < 2; ++ct)
            bf[ct] = *(const short8*)&Bs[(wave * 2 + ct) * 512 + (quad * 16 + m16) * 8];
#pragma unroll
        for (int rt = 0; rt < 7; ++rt)
#pragma unroll
            for (int ct = 0; ct < 2; ++ct)
                acc[rt][ct] = __builtin_amdgcn_mfma_f32_16x16x32_bf16(af[rt], bf[ct], acc[rt][ct], 0, 0, 0);
        __syncthreads();
    }
    // h2 (pre-relu) -> hs (stride 260)
#pragma unroll
    for (int rt = 0; rt < 7; ++rt)
#pragma unroll
        for (int ct = 0; ct < 2; ++ct)
#pragma unroll
            for (int i = 0; i < 4; ++i)
                hs[(rt * 16 + quad * 4 + i) * 260 + wave * 32 + ct * 16 + m16] = f2bf(acc[rt][ct][i]);
    __syncthreads();
    // attention 2: in-place relu'd write-back (hs becomes `combined` node part) + alpha out
    float* alf = out + 6 * B_SZ;
#pragma unroll
    for (int gg = 0; gg < 2; ++gg) {
        int gl = wave * 2 + gg;
        long b = gbase + gl;
        attn_graph<260, true>(&hs[gl * 7 * 260], adjs, avec,
                              &hs[gl * 7 * 260], 260, alf + b * 49, lane);
    }
    __syncthreads();
    // head GEMM: 16x48, K=2048 split 8 ways. Wave w owns k in [w*256,(w+1)*256):
    // node slice n==w for w<7, context for w==7. A-frag lane m16 = graph.
    floatx4 acc3[3];
#pragma unroll
    for (int ct = 0; ct < 3; ++ct) acc3[ct] = (floatx4){0.f, 0.f, 0.f, 0.f};
    const long wk = (long)wave * 256;
#pragma unroll
    for (int s = 0; s < 8; ++s) {
        int kk = s * 32;
        short8 a;
        if (wave < 7) a = *(const short8*)&hs[(m16 * 7 + wave) * 260 + kk + quad * 8];
        else          a = *(const short8*)&ctxs[m16 * 260 + kk + quad * 8];
#pragma unroll
        for (int ct = 0; ct < 3; ++ct) {
            short8 bh = *(const short8*)(Whb + (long)(ct * 16 + m16) * COMB + wk + kk + quad * 8);
            acc3[ct] = __builtin_amdgcn_mfma_f32_16x16x32_bf16(a, bh, acc3[ct], 0, 0, 0);
        }
    }
#pragma unroll
    for (int ct = 0; ct < 3; ++ct)
#pragma unroll
        for (int i = 0; i < 4; ++i)
            red[wave * 768 + (quad * 4 + i) * 48 + ct * 16 + m16] = acc3[ct][i];
    __syncthreads();
    {   // reduce 8 partials -> fin[768]
        float s = 0.f;
#pragma unroll
        for (int w = 0; w < 8; ++w) s += red[w * 768 + tid];
        fin[tid] = s;
        if (tid < 256) {
            float s2 = 0.f;
#pragma unroll
            for (int w = 0; w < 8; ++w) s2 += red[w * 768 + 512 + tid];
            fin[512 + tid] = s2;
        }
    }
    __syncthreads();
    if (tid < 16) {  // finalize MLPs, one thread per graph
        const int g = tid;
        const long b = gbase + g;
        const float* g48 = &fin[g * 48];
        float t1[32], r1[16];
#pragma unroll
        for (int k = 0; k < 32; ++k) t1[k] = fmaxf(g48[k] + wh1_b[k], 0.f);
#pragma unroll
        for (int k = 0; k < 16; ++k) r1[k] = tanhf(g48[32 + k] + rh1_b[k]);
        float t2[16];
#pragma unroll
        for (int jj = 0; jj < 16; ++jj) {
            float s = wh2_b[jj];
            for (int k = 0; k < 32; ++k) s += wh2_w[jj * 32 + k] * t1[k];
            t2[jj] = fmaxf(s, 0.f);
        }
        float rw[5], m = -1e30f;
#pragma unroll
        for (int o = 0; o < 5; ++o) {
            float s = wh3_b[o];
            for (int jj = 0; jj < 16; ++jj) s += wh3_w[o * 16 + jj] * t2[jj];
            rw[o] = s; m = fmaxf(m, s);
        }
        float se = 0.f;
#pragma unroll
        for (int o = 0; o < 5; ++o) { rw[o] = __expf(rw[o] - m); se += rw[o]; }
        float inv = 1.f / se, wp = 0.f;
#pragma unroll
        for (int o = 0; o < 5; ++o) {
            float w = rw[o] * inv;
            out[B_SZ + b * 5 + o] = w;
            wp += w * base_preds[b * 5 + o];
        }
        float rs = rh2_b[0];
#pragma unroll
        for (int k = 0; k < 16; ++k) rs += rh2_w[k] * r1[k];
        out[b] = fmaxf(wp + rs * 0.05f, 0.05f);
    }
}

extern "C" void kernel_launch(void* const* d_in, const int* in_sizes, int n_in,
                              void* d_out, int out_size, void* d_ws, size_t ws_size,
                              hipStream_t stream) {
    const float* node_feats = (const float*)d_in[0];
    const float* adj        = (const float*)d_in[1];
    const float* context    = (const float*)d_in[2];
    const float* base_preds = (const float*)d_in[3];
    const float* W1         = (const float*)d_in[4];
    const float* a1         = (const float*)d_in[5];
    const float* W2         = (const float*)d_in[6];
    const float* a2         = (const float*)d_in[7];
    const float* wh1_w = (const float*)d_in[8];
    const float* wh1_b = (const float*)d_in[9];
    const float* wh2_w = (const float*)d_in[10];
    const float* wh2_b = (const float*)d_in[11];
    const float* wh3_w = (const float*)d_in[12];
    const float* wh3_b = (const float*)d_in[13];
    const float* rh1_w = (const float*)d_in[14];
    const float* rh1_b = (const float*)d_in[15];
    const float* rh2_w = (const float*)d_in[16];
    const float* rh2_b = (const float*)d_in[17];
    float* out = (float*)d_out;

    char* ws = (char*)d_ws;
    const size_t HB = (size_t)B_SZ * NN * HID * 2;  // x2: 58,720,256 B
    us* x2  = (us*)ws;
    us* W1b = (us*)(ws + HB);         // 131072 shorts
    us* W2b = W1b + 131072;           // 65536
    us* Whb = W2b + 65536;            // 98304 (wh1_w || rh1_w)

    pack_weights<<<288, 256, 0, stream>>>(W1, W2, wh1_w, rh1_w, W1b);

    fused_g1<<<1024, 512, 81104, stream>>>(node_feats, W1b, adj, a1, x2);

    fused_rest<<<1024, 512, 118992, stream>>>(x2, W2b, Whb, adj, a2, context,
                                              wh1_b, wh2_w, wh2_b, wh3_w, wh3_b,
                                              rh1_b, rh2_w, rh2_b, base_preds, out);
}

// Round 4
// 540.776 us; speedup vs baseline: 1.5601x; 1.0018x over previous
//
#include <hip/hip_runtime.h>

#define B_SZ 16384
#define NN 7
#define HID 256
#define COMB 2048

typedef __attribute__((ext_vector_type(8))) short short8;
typedef __attribute__((ext_vector_type(4))) float floatx4;
typedef __attribute__((ext_vector_type(4))) unsigned short ushortx4;
typedef unsigned short us;

__device__ __forceinline__ float bf2f(us u) {
    union { unsigned int i; float f; } v; v.i = ((unsigned int)u) << 16; return v.f;
}
__device__ __forceinline__ us f2bf(float f) {  // RNE
    union { unsigned int i; float f; } v; v.f = f;
    return (us)((v.i + 0x7FFFu + ((v.i >> 16) & 1u)) >> 16);
}
__device__ __forceinline__ us f2bf_fast(float f) {  // round-half-up (hot path)
    union { unsigned int i; float f; } v; v.f = f;
    return (us)((v.i + 0x8000u) >> 16);
}
__device__ __forceinline__ void gl_lds16(const us* g, us* l) {
    __builtin_amdgcn_global_load_lds(
        (const __attribute__((address_space(1))) unsigned int*)g,
        (__attribute__((address_space(3))) unsigned int*)l, 16, 0, 0);
}

// Pack W1 (131072), W2 (65536), wh1_w (65536), rh1_w (32768) fp32 -> contiguous bf16 dst.
__global__ __launch_bounds__(256) void pack_weights(const float* __restrict__ W1,
                                                    const float* __restrict__ W2,
                                                    const float* __restrict__ wh1,
                                                    const float* __restrict__ rh1,
                                                    us* __restrict__ dst) {
    int i = (blockIdx.x * 256 + threadIdx.x) * 4;
    if (i >= 294912) return;
    const float* src; int off;
    if (i < 131072)      { src = W1;  off = i; }
    else if (i < 196608) { src = W2;  off = i - 131072; }
    else if (i < 262144) { src = wh1; off = i - 196608; }
    else                 { src = rh1; off = i - 262144; }
    floatx4 v = *(const floatx4*)(src + off);
    ushortx4 o = {f2bf(v[0]), f2bf(v[1]), f2bf(v[2]), f2bf(v[3])};
    *(ushortx4*)(dst + i) = o;
}

// GAT attention for ONE graph by one wave; verified round-2/3 structure.
// hb rows stride SRC_STRIDE (shorts). dst stride dstStride.
template <int SRC_STRIDE, bool WRITE_ALPHA>
__device__ __forceinline__ void attn_graph(const us* hb, const float* adjs, const float* avec,
                                           us* dst, int dstStride, float* alpha_dst, int lane) {
    float hv[NN][4];
#pragma unroll
    for (int n = 0; n < NN; ++n) {
        ushortx4 r = *(const ushortx4*)(hb + n * SRC_STRIDE + lane * 4);
        hv[n][0] = bf2f(r[0]); hv[n][1] = bf2f(r[1]);
        hv[n][2] = bf2f(r[2]); hv[n][3] = bf2f(r[3]);
    }
    floatx4 ai = *(const floatx4*)(avec + lane * 4);
    floatx4 aj = *(const floatx4*)(avec + HID + lane * 4);
    float si[NN], sj[NN];
#pragma unroll
    for (int n = 0; n < NN; ++n) {
        float pi = hv[n][0] * ai[0] + hv[n][1] * ai[1] + hv[n][2] * ai[2] + hv[n][3] * ai[3];
        float pj = hv[n][0] * aj[0] + hv[n][1] * aj[1] + hv[n][2] * aj[2] + hv[n][3] * aj[3];
#pragma unroll
        for (int off = 32; off; off >>= 1) {
            pi += __shfl_xor(pi, off);
            pj += __shfl_xor(pj, off);
        }
        si[n] = pi; sj[n] = pj;
    }
    const int j = lane & 7;
    float sjm = sj[0];
    if (j == 1) sjm = sj[1];
    if (j == 2) sjm = sj[2];
    if (j == 3) sjm = sj[3];
    if (j == 4) sjm = sj[4];
    if (j == 5) sjm = sj[5];
    if (j == 6) sjm = sj[6];
    const int jc = (j < 7) ? j : 0;
    float alpha[NN];
#pragma unroll
    for (int i = 0; i < NN; ++i) {
        float x = si[i] + sjm;
        x = (x >= 0.f) ? x : 0.2f * x;                     // leaky_relu 0.2
        bool ok = (j < 7) && (adjs[i * 7 + jc] != 0.f);    // adj mask + dummy col
        float e = ok ? x : -1e30f;
        float m = e;
        m = fmaxf(m, __shfl_xor(m, 1, 8));
        m = fmaxf(m, __shfl_xor(m, 2, 8));
        m = fmaxf(m, __shfl_xor(m, 4, 8));
        float ex = ok ? __expf(e - m) : 0.f;
        float s = ex;
        s += __shfl_xor(s, 1, 8);
        s += __shfl_xor(s, 2, 8);
        s += __shfl_xor(s, 4, 8);
        alpha[i] = (s > 0.f) ? ex * __frcp_rn(s) : 0.f;    // nan_to_num path
    }
    if (WRITE_ALPHA && lane < 7) {
#pragma unroll
        for (int i = 0; i < NN; ++i) alpha_dst[i * NN + lane] = alpha[i];
    }
#pragma unroll
    for (int i = 0; i < NN; ++i) {
        floatx4 o = (floatx4){0.f, 0.f, 0.f, 0.f};
#pragma unroll
        for (int jj = 0; jj < NN; ++jj) {
            float a = __shfl(alpha[i], jj, 8);
            o[0] += a * hv[jj][0]; o[1] += a * hv[jj][1];
            o[2] += a * hv[jj][2]; o[3] += a * hv[jj][3];
        }
        ushortx4 st = {f2bf(fmaxf(o[0], 0.f)), f2bf(fmaxf(o[1], 0.f)),
                       f2bf(fmaxf(o[2], 0.f)), f2bf(fmaxf(o[3], 0.f))};
        *(ushortx4*)(dst + i * dstStride + lane * 4) = st;   // relu
    }
}

// LDS chunk-major A layout: chunk(r, k8) = (r>>3)*64 + (r&7)*8 + k8, each chunk 16B (8 bf16).
// Fragment read (row rt*16+m16, k = t*32+quad*8): chunk = (rt*2+(m16>>3))*64 + (m16&7)*8 + t*4+quad.

// ---------------- Kernel A: GEMM1 (fp32 A) + attention 1 -> x2 ----------------
// 2048 blocks x 512 threads; block = 8 graphs = 56 rows (A-tile padded to 64).
// B (W1) fragments loaded per-wave straight from L2 (no LDS, no 2nd staging barrier).
__global__ __launch_bounds__(512, 4) void fused_g1(const float* __restrict__ Af,
                                                   const us* __restrict__ W1b,
                                                   const float* __restrict__ adj,
                                                   const float* __restrict__ avec,
                                                   us* __restrict__ x2g) {
    __shared__ __attribute__((aligned(16))) us As[4096];      // 64 rows x 64 k bf16
    __shared__ __attribute__((aligned(16))) us hs[56 * 264];  // h1, stride 264
    __shared__ float adjs[52];
    const int tid = threadIdx.x;
    const int wave = tid >> 6, lane = tid & 63;
    const int quad = lane >> 4, m16 = lane & 15;
    const long rowBase = (long)blockIdx.x * 56;
    if (tid < 49) adjs[tid] = adj[tid];

    floatx4 acc[4][2];
#pragma unroll
    for (int rt = 0; rt < 4; ++rt)
#pragma unroll
        for (int ct = 0; ct < 2; ++ct) acc[rt][ct] = (floatx4){0.f, 0.f, 0.f, 0.f};

    const int r = tid >> 3, kq8 = tid & 7;
    long rowA = rowBase + r; if (rowA > 114687) rowA = 114687;   // tail clamp
    const float* aptr = Af + rowA * 512 + kq8 * 8;
    us* wdst = &As[((r >> 3) * 64 + (r & 7) * 8 + kq8) * 8];
    const int colb = wave * 32;

    for (int s = 0; s < 8; ++s) {
        const int k0 = s * 64;
        floatx4 v0 = *(const floatx4*)(aptr + k0);
        floatx4 v1 = *(const floatx4*)(aptr + k0 + 4);
        short8 sv;
        sv[0] = f2bf_fast(v0[0]); sv[1] = f2bf_fast(v0[1]);
        sv[2] = f2bf_fast(v0[2]); sv[3] = f2bf_fast(v0[3]);
        sv[4] = f2bf_fast(v1[0]); sv[5] = f2bf_fast(v1[1]);
        sv[6] = f2bf_fast(v1[2]); sv[7] = f2bf_fast(v1[3]);
        *(short8*)wdst = sv;
        __syncthreads();
#pragma unroll
        for (int t = 0; t < 2; ++t) {
            short8 b0 = *(const short8*)(W1b + (long)(colb + m16) * 512 + k0 + t * 32 + quad * 8);
            short8 b1 = *(const short8*)(W1b + (long)(colb + 16 + m16) * 512 + k0 + t * 32 + quad * 8);
            short8 a[4];
#pragma unroll
            for (int rt = 0; rt < 4; ++rt)
                a[rt] = *(const short8*)&As[((rt * 2 + (m16 >> 3)) * 64 + (m16 & 7) * 8 + t * 4 + quad) * 8];
#pragma unroll
            for (int rt = 0; rt < 4; ++rt) {
                acc[rt][0] = __builtin_amdgcn_mfma_f32_16x16x32_bf16(a[rt], b0, acc[rt][0], 0, 0, 0);
                acc[rt][1] = __builtin_amdgcn_mfma_f32_16x16x32_bf16(a[rt], b1, acc[rt][1], 0, 0, 0);
            }
        }
        __syncthreads();
    }
    // h1 pre-relu -> hs (rows < 56). C-layout: row = quad*4+i, col = m16.
#pragma unroll
    for (int rt = 0; rt < 4; ++rt)
#pragma unroll
        for (int ct = 0; ct < 2; ++ct)
#pragma unroll
            for (int i = 0; i < 4; ++i) {
                int row = rt * 16 + quad * 4 + i;
                if (row < 56) hs[row * 264 + wave * 32 + ct * 16 + m16] = f2bf(acc[rt][ct][i]);
            }
    __syncthreads();
    // attention 1: wave = graph; x2 row-major (block-padded 64 rows)
    attn_graph<264, false>(&hs[wave * 7 * 264], adjs, avec,
                           x2g + ((long)blockIdx.x * 64 + wave * 7) * 256, 256, nullptr, lane);
}

// ------- Kernel B: GEMM2 + attention 2 + head GEMM + reduce + finalize -------
// 2048 blocks x 512 threads; block = 8 graphs. x2 staged via coalesced gl_lds16
// (one 1KB instruction per wave = 8 rows x 128B contiguous chunks).
__global__ __launch_bounds__(512, 4) void fused_rest(const us* __restrict__ x2g,
                                                     const us* __restrict__ W2b,
                                                     const us* __restrict__ Whb,
                                                     const float* __restrict__ adj,
                                                     const float* __restrict__ avec,
                                                     const float* __restrict__ context,
                                                     const float* __restrict__ wh1_b,
                                                     const float* __restrict__ wh2_w,
                                                     const float* __restrict__ wh2_b,
                                                     const float* __restrict__ wh3_w,
                                                     const float* __restrict__ wh3_b,
                                                     const float* __restrict__ rh1_b,
                                                     const float* __restrict__ rh2_w,
                                                     const float* __restrict__ rh2_b,
                                                     const float* __restrict__ base_preds,
                                                     float* __restrict__ out) {
    __shared__ __attribute__((aligned(16))) us As[4096];       // 64 x 64k bf16
    __shared__ __attribute__((aligned(16))) us hs[56 * 264];   // h2 / combined nodes
    __shared__ __attribute__((aligned(16))) us ctxs[8 * 264];  // context bf16
    __shared__ float red[8 * 384];                             // head partials per wave
    __shared__ float fin[384];
    __shared__ float adjs[52];
    const int tid = threadIdx.x;
    const int wave = tid >> 6, lane = tid & 63;
    const int quad = lane >> 4, m16 = lane & 15;
    const long rowBaseX = (long)blockIdx.x * 64;
    const long gbase = (long)blockIdx.x * 8;
    if (tid < 49) adjs[tid] = adj[tid];
    {   // stage context: 8 rows x 256 fp32 -> bf16
        int cr = tid >> 6, c4 = (tid & 63) * 4;
        floatx4 cv = *(const floatx4*)(context + (gbase + cr) * 256 + c4);
        ushortx4 st = {f2bf(cv[0]), f2bf(cv[1]), f2bf(cv[2]), f2bf(cv[3])};
        *(ushortx4*)&ctxs[cr * 264 + c4] = st;
    }

    floatx4 acc[4][2];
#pragma unroll
    for (int rt = 0; rt < 4; ++rt)
#pragma unroll
        for (int ct = 0; ct < 2; ++ct) acc[rt][ct] = (floatx4){0.f, 0.f, 0.f, 0.f};
    const int colb = wave * 32;

    for (int s = 0; s < 4; ++s) {
        const int k0 = s * 64;
        // wave w: rows w*8..w*8+7, each 128B contiguous (8 chunks); lane = rg*8+kq
        gl_lds16(x2g + (rowBaseX + wave * 8 + (lane >> 3)) * 256 + k0 + (lane & 7) * 8,
                 &As[wave * 512]);
        __syncthreads();
#pragma unroll
        for (int t = 0; t < 2; ++t) {
            short8 b0 = *(const short8*)(W2b + (long)(colb + m16) * 256 + k0 + t * 32 + quad * 8);
            short8 b1 = *(const short8*)(W2b + (long)(colb + 16 + m16) * 256 + k0 + t * 32 + quad * 8);
            short8 a[4];
#pragma unroll
            for (int rt = 0; rt < 4; ++rt)
                a[rt] = *(const short8*)&As[((rt * 2 + (m16 >> 3)) * 64 + (m16 & 7) * 8 + t * 4 + quad) * 8];
#pragma unroll
            for (int rt = 0; rt < 4; ++rt) {
                acc[rt][0] = __builtin_amdgcn_mfma_f32_16x16x32_bf16(a[rt], b0, acc[rt][0], 0, 0, 0);
                acc[rt][1] = __builtin_amdgcn_mfma_f32_16x16x32_bf16(a[rt], b1, acc[rt][1], 0, 0, 0);
            }
        }
        __syncthreads();
    }
#pragma unroll
    for (int rt = 0; rt < 4; ++rt)
#pragma unroll
        for (int ct = 0; ct < 2; ++ct)
#pragma unroll
            for (int i = 0; i < 4; ++i) {
                int row = rt * 16 + quad * 4 + i;
                if (row < 56) hs[row * 264 + wave * 32 + ct * 16 + m16] = f2bf(acc[rt][ct][i]);
            }
    __syncthreads();
    // attention 2: in-place (hs -> combined node part), alpha -> out
    float* alf = out + 6 * B_SZ;
    attn_graph<264, true>(&hs[wave * 7 * 264], adjs, avec,
                          &hs[wave * 7 * 264], 264, alf + (gbase + wave) * 49, lane);
    __syncthreads();
    // head GEMM: 8 graphs x 48 outs, K=2048 split across 8 waves (wave=node slice / ctx)
    floatx4 acc3[3];
#pragma unroll
    for (int ct = 0; ct < 3; ++ct) acc3[ct] = (floatx4){0.f, 0.f, 0.f, 0.f};
    const int g = m16 & 7;
#pragma unroll
    for (int s2 = 0; s2 < 8; ++s2) {
        const int kk = s2 * 32;
        short8 a;
        if (wave < 7) a = *(const short8*)&hs[(g * 7 + wave) * 264 + kk + quad * 8];
        else          a = *(const short8*)&ctxs[g * 264 + kk + quad * 8];
#pragma unroll
        for (int ct = 0; ct < 3; ++ct) {
            short8 bh = *(const short8*)(Whb + (long)(ct * 16 + m16) * COMB + wave * 256 + kk + quad * 8);
            acc3[ct] = __builtin_amdgcn_mfma_f32_16x16x32_bf16(a, bh, acc3[ct], 0, 0, 0);
        }
    }
#pragma unroll
    for (int ct = 0; ct < 3; ++ct)
#pragma unroll
        for (int i = 0; i < 4; ++i) {
            int g2 = quad * 4 + i;                 // C row = graph
            if (g2 < 8) red[wave * 384 + g2 * 48 + ct * 16 + m16] = acc3[ct][i];
        }
    __syncthreads();
    if (tid < 384) {
        float ssum = 0.f;
#pragma unroll
        for (int w = 0; w < 8; ++w) ssum += red[w * 384 + tid];
        fin[tid] = ssum;
    }
    __syncthreads();
    if (tid < 8) {  // finalize MLPs, one thread per graph
        const long b = gbase + tid;
        const float* g48 = &fin[tid * 48];
        float t1[32], r1[16];
#pragma unroll
        for (int k = 0; k < 32; ++k) t1[k] = fmaxf(g48[k] + wh1_b[k], 0.f);
#pragma unroll
        for (int k = 0; k < 16; ++k) r1[k] = tanhf(g48[32 + k] + rh1_b[k]);
        float t2[16];
#pragma unroll
        for (int jj = 0; jj < 16; ++jj) {
            float s = wh2_b[jj];
            for (int k = 0; k < 32; ++k) s += wh2_w[jj * 32 + k] * t1[k];
            t2[jj] = fmaxf(s, 0.f);
        }
        float rw[5], m = -1e30f;
#pragma unroll
        for (int o = 0; o < 5; ++o) {
            float s = wh3_b[o];
            for (int jj = 0; jj < 16; ++jj) s += wh3_w[o * 16 + jj] * t2[jj];
            rw[o] = s; m = fmaxf(m, s);
        }
        float se = 0.f;
#pragma unroll
        for (int o = 0; o < 5; ++o) { rw[o] = __expf(rw[o] - m); se += rw[o]; }
        float inv = 1.f / se, wp = 0.f;
#pragma unroll
        for (int o = 0; o < 5; ++o) {
            float w = rw[o] * inv;
            out[B_SZ + b * 5 + o] = w;
            wp += w * base_preds[b * 5 + o];
        }
        float rs = rh2_b[0];
#pragma unroll
        for (int k = 0; k < 16; ++k) rs += rh2_w[k] * r1[k];
        out[b] = fmaxf(wp + rs * 0.05f, 0.05f);
    }
}

extern "C" void kernel_launch(void* const* d_in, const int* in_sizes, int n_in,
                              void* d_out, int out_size, void* d_ws, size_t ws_size,
                              hipStream_t stream) {
    const float* node_feats = (const float*)d_in[0];
    const float* adj        = (const float*)d_in[1];
    const float* context    = (const float*)d_in[2];
    const float* base_preds = (const float*)d_in[3];
    const float* W1         = (const float*)d_in[4];
    const float* a1         = (const float*)d_in[5];
    const float* W2         = (const float*)d_in[6];
    const float* a2         = (const float*)d_in[7];
    const float* wh1_w = (const float*)d_in[8];
    const float* wh1_b = (const float*)d_in[9];
    const float* wh2_w = (const float*)d_in[10];
    const float* wh2_b = (const float*)d_in[11];
    const float* wh3_w = (const float*)d_in[12];
    const float* wh3_b = (const float*)d_in[13];
    const float* rh1_w = (const float*)d_in[14];
    const float* rh1_b = (const float*)d_in[15];
    const float* rh2_w = (const float*)d_in[16];
    const float* rh2_b = (const float*)d_in[17];
    float* out = (float*)d_out;

    char* ws = (char*)d_ws;
    const size_t X2B = (size_t)2048 * 64 * 256 * 2;  // 67,108,864 B (64-row padded blocks)
    us* x2  = (us*)ws;
    us* W1b = (us*)(ws + X2B);        // 131072 shorts
    us* W2b = W1b + 131072;           // 65536
    us* Whb = W2b + 65536;            // 98304 (wh1_w || rh1_w)

    pack_weights<<<288, 256, 0, stream>>>(W1, W2, wh1_w, rh1_w, W1b);

    fused_g1<<<2048, 512, 0, stream>>>(node_feats, W1b, adj, a1, x2);

    fused_rest<<<2048, 512, 0, stream>>>(x2, W2b, Whb, adj, a2, context,
                                         wh1_b, wh2_w, wh2_b, wh3_w, wh3_b,
                                         rh1_b, rh2_w, rh2_b, base_preds, out);
}